// Round 1
// baseline (225.181 us; speedup 1.0000x reference)
//
#include <hip/hip_runtime.h>
#include <hip/hip_bf16.h>
#include <stdint.h>

#define N 4096
#define K 2048
#define BM 128
#define BN 128
#define KT 64
#define NCB (N / BN)
#define NRB (N / BM)
#define NEG_INF (-__builtin_inff())

typedef float f32x4 __attribute__((ext_vector_type(4)));
typedef short short8 __attribute__((ext_vector_type(8)));

__device__ __forceinline__ unsigned short f2bf(float x) {
    unsigned u = __float_as_uint(x);
    u += 0x7FFFu + ((u >> 16) & 1u);
    return (unsigned short)(u >> 16);
}
__device__ __forceinline__ float bf2f(unsigned short b) {
    return __uint_as_float(((unsigned)b) << 16);
}

// log-sum-exp merge of (m,s,t) stats; s==0 encodes "empty" (m == -inf)
__device__ __forceinline__ void merge3(float& m, float& s, float& t,
                                       float m2, float s2, float t2) {
    float mm = fmaxf(m, m2);
    float e1 = (s  > 0.f) ? __expf(m  - mm) : 0.f;
    float e2 = (s2 > 0.f) ? __expf(m2 - mm) : 0.f;
    s = s * e1 + s2 * e2;
    t = t * e1 + t2 * e2;
    m = mm;
}

// --- kernel 1: row squared-norms + fp32 -> (hi,lo) bf16 split ---------------
__global__ __launch_bounds__(256) void k_prep(const float* __restrict__ X,
                                              unsigned short* __restrict__ Xhi,
                                              unsigned short* __restrict__ Xlo,
                                              float* __restrict__ sq) {
    const int row  = blockIdx.x * 4 + (threadIdx.x >> 6);
    const int lane = threadIdx.x & 63;
    const float4* xr = (const float4*)(X + (size_t)row * K);
    ushort4* hr = (ushort4*)(Xhi + (size_t)row * K);
    ushort4* lr = (ushort4*)(Xlo + (size_t)row * K);
    float s = 0.f;
#pragma unroll
    for (int i = 0; i < 8; ++i) {
        int idx = lane + i * 64;
        float4 v = xr[idx];
        ushort4 h, l;
        h.x = f2bf(v.x); l.x = f2bf(v.x - bf2f(h.x));
        h.y = f2bf(v.y); l.y = f2bf(v.y - bf2f(h.y));
        h.z = f2bf(v.z); l.z = f2bf(v.z - bf2f(h.z));
        h.w = f2bf(v.w); l.w = f2bf(v.w - bf2f(h.w));
        s += v.x * v.x + v.y * v.y + v.z * v.z + v.w * v.w;
        hr[idx] = h; lr[idx] = l;
    }
#pragma unroll
    for (int off = 32; off > 0; off >>= 1) s += __shfl_xor(s, off);
    if (lane == 0) sq[row] = s;
}

// --- kernel 2: fused 128x128 Gram tile (3-term bf16 MFMA) + partial softmax -
__global__ __launch_bounds__(256, 2) void k_tile(const unsigned short* __restrict__ Xhi,
                                                 const unsigned short* __restrict__ Xlo,
                                                 const int* __restrict__ tg,
                                                 const float* __restrict__ sq,
                                                 float* __restrict__ part) {
    __shared__ __align__(16) char lds[65536]; // Ahi|Alo|Bhi|Blo, 16KB each
    const int tid = threadIdx.x;
    const int cb = blockIdx.x, rb = blockIdx.y;
    const int lane = tid & 63;
    const int wid = tid >> 6;
    const int wr = wid >> 1, wc = wid & 1;
    const int l15 = lane & 15, l4 = lane >> 4;

    f32x4 acc[4][4] = {};

    for (int kt = 0; kt < K / KT; ++kt) {
        __syncthreads();
        // stage 4 x (128 rows x 64 bf16) with XOR slot swizzle (G4)
#pragma unroll
        for (int t = 0; t < 16; ++t) {
            int id = tid + t * 256;          // 0..4095
            int region = id >> 10;           // 0=Ahi 1=Alo 2=Bhi 3=Blo
            int s = id & 1023;
            int row = s >> 3, sl = s & 7;
            int gr = ((region >= 2) ? cb * BN : rb * BM) + row;
            const unsigned short* src = (region & 1) ? Xlo : Xhi;
            short8 v = *(const short8*)(src + (size_t)gr * K + kt * KT + sl * 8);
            *(short8*)(lds + region * 16384 + row * 128 + ((sl ^ (row & 7)) << 4)) = v;
        }
        __syncthreads();
#pragma unroll
        for (int ks = 0; ks < 2; ++ks) {
            short8 ah[4], al[4], bh[4], bl[4];
#pragma unroll
            for (int i = 0; i < 4; ++i) {
                int ar = wr * 64 + i * 16 + l15;
                int ao = ar * 128 + ((((ks << 2) | l4) ^ (ar & 7)) << 4);
                ah[i] = *(const short8*)(lds + ao);
                al[i] = *(const short8*)(lds + 16384 + ao);
                int br = wc * 64 + i * 16 + l15;
                int bo = br * 128 + ((((ks << 2) | l4) ^ (br & 7)) << 4);
                bh[i] = *(const short8*)(lds + 32768 + bo);
                bl[i] = *(const short8*)(lds + 49152 + bo);
            }
#pragma unroll
            for (int mt = 0; mt < 4; ++mt)
#pragma unroll
                for (int nt = 0; nt < 4; ++nt) {
                    acc[mt][nt] = __builtin_amdgcn_mfma_f32_16x16x32_bf16(ah[mt], bh[nt], acc[mt][nt], 0, 0, 0);
                    acc[mt][nt] = __builtin_amdgcn_mfma_f32_16x16x32_bf16(ah[mt], bl[nt], acc[mt][nt], 0, 0, 0);
                    acc[mt][nt] = __builtin_amdgcn_mfma_f32_16x16x32_bf16(al[mt], bh[nt], acc[mt][nt], 0, 0, 0);
                }
        }
    }

    // ---- epilogue: dist + per-row online-softmax partials over this col-block
    __syncthreads();
    float* sqA = (float*)lds;
    float* sqB = sqA + 128;
    int* tgA = (int*)(sqB + 128);
    int* tgB = tgA + 128;
    if (tid < 128) {
        sqA[tid] = sq[rb * BM + tid];
        sqB[tid] = sq[cb * BN + tid];
        tgA[tid] = tg[rb * BM + tid];
        tgB[tid] = tg[cb * BN + tid];
    }
    __syncthreads();
    float* stats = (float*)(lds + 8192); // [128 rows][2 wc][6]

#pragma unroll
    for (int mt = 0; mt < 4; ++mt) {
#pragma unroll
        for (int rg = 0; rg < 4; ++rg) {
            int rl = wr * 64 + mt * 16 + l4 * 4 + rg;
            float sqi = sqA[rl];
            int ti = tgA[rl];
            float d[4]; bool ps[4];
            float mp = NEG_INF, mn = NEG_INF;
#pragma unroll
            for (int nt = 0; nt < 4; ++nt) {
                int cl = wc * 64 + nt * 16 + l15;
                float g = acc[mt][nt][rg];
                float dd = sqrtf(fmaxf(sqi + sqB[cl] - 2.0f * g, 1e-12f));
                d[nt] = dd;
                ps[nt] = (ti == tgB[cl]);
                if (ps[nt]) mp = fmaxf(mp, dd); else mn = fmaxf(mn, -dd);
            }
            // row-wide max across the 16 lanes holding this row
#pragma unroll
            for (int off = 1; off < 16; off <<= 1) {
                mp = fmaxf(mp, __shfl_xor(mp, off));
                mn = fmaxf(mn, __shfl_xor(mn, off));
            }
            float sp = 0.f, tp = 0.f, sn = 0.f, tn = 0.f;
#pragma unroll
            for (int nt = 0; nt < 4; ++nt) {
                // arg <= 0 always: own value contributed to the max pre-reduce
                float arg = ps[nt] ? (d[nt] - mp) : (-d[nt] - mn);
                float e = __expf(arg);
                if (ps[nt]) { sp += e; tp += e * d[nt]; }
                else        { sn += e; tn += e * d[nt]; }
            }
#pragma unroll
            for (int off = 1; off < 16; off <<= 1) {
                sp += __shfl_xor(sp, off);
                tp += __shfl_xor(tp, off);
                sn += __shfl_xor(sn, off);
                tn += __shfl_xor(tn, off);
            }
            if (l15 == 0) {
                float* p = stats + (rl * 2 + wc) * 6;
                p[0] = mp; p[1] = sp; p[2] = tp;
                p[3] = mn; p[4] = sn; p[5] = tn;
            }
        }
    }
    __syncthreads();
    if (tid < 128) {
        const float* a = stats + (tid * 2 + 0) * 6;
        const float* b = stats + (tid * 2 + 1) * 6;
        float mp = a[0], sp = a[1], tp = a[2];
        float mn = a[3], sn = a[4], tn = a[5];
        merge3(mp, sp, tp, b[0], b[1], b[2]);
        merge3(mn, sn, tn, b[3], b[4], b[5]);
        float* o = part + ((size_t)cb * N + rb * BM + tid) * 6;
        o[0] = mp; o[1] = sp; o[2] = tp;
        o[3] = mn; o[4] = sn; o[5] = tn;
    }
}

// --- kernel 3: merge col-block partials per row -> hinge ---------------------
__global__ __launch_bounds__(256) void k_rowmerge(const float* __restrict__ part,
                                                  float* __restrict__ hinge) {
    int r = blockIdx.x * 256 + threadIdx.x;
    float mp = NEG_INF, sp = 0.f, tp = 0.f;
    float mn = NEG_INF, sn = 0.f, tn = 0.f;
    for (int cb = 0; cb < NCB; ++cb) {
        const float* p = part + ((size_t)cb * N + r) * 6;
        merge3(mp, sp, tp, p[0], p[1], p[2]);
        merge3(mn, sn, tn, p[3], p[4], p[5]);
    }
    float dap = tp / sp;
    float dan = tn / sn;
    hinge[r] = fmaxf(dap - dan + 0.3f, 0.f);
}

// --- kernel 4: mean ----------------------------------------------------------
__global__ __launch_bounds__(256) void k_sum(const float* __restrict__ hinge,
                                             float* __restrict__ out) {
    float s = 0.f;
    for (int i = threadIdx.x; i < N; i += 256) s += hinge[i];
    __shared__ float red[256];
    red[threadIdx.x] = s;
    __syncthreads();
    for (int k = 128; k > 0; k >>= 1) {
        if (threadIdx.x < k) red[threadIdx.x] += red[threadIdx.x + k];
        __syncthreads();
    }
    if (threadIdx.x == 0) out[0] = red[0] * (1.0f / N);
}

extern "C" void kernel_launch(void* const* d_in, const int* in_sizes, int n_in,
                              void* d_out, int out_size, void* d_ws, size_t ws_size,
                              hipStream_t stream) {
    (void)in_sizes; (void)n_in; (void)out_size; (void)ws_size;
    const float* X  = (const float*)d_in[0];
    const int*   tg = (const int*)d_in[1];

    char* ws = (char*)d_ws;
    float* sq    = (float*)ws;                 // 16 KB
    float* hinge = (float*)(ws + 16384);       // 16 KB
    float* part  = (float*)(ws + 32768);       // 4096*32*6 floats = 3 MB
    unsigned short* Xhi = (unsigned short*)(ws + 3178496);   // 16 MB
    unsigned short* Xlo = Xhi + (size_t)N * K;                // 16 MB

    k_prep<<<N / 4, 256, 0, stream>>>(X, Xhi, Xlo, sq);
    k_tile<<<dim3(NCB, NRB), 256, 0, stream>>>(Xhi, Xlo, tg, sq, part);
    k_rowmerge<<<N / 256, 256, 0, stream>>>(part, hinge);
    k_sum<<<1, 256, 0, stream>>>(hinge, (float*)d_out);
}

// Round 2
// 108.632 us; speedup vs baseline: 2.0729x; 2.0729x over previous
//
#include <hip/hip_runtime.h>
#include <hip/hip_bf16.h>
#include <stdint.h>

#define N 4096
#define K 2048
#define BM 128
#define BN 128
#define KT 64
#define NCB (N / BN)
#define NRB (N / BM)
#define NEG_INF (-__builtin_inff())

typedef float f32x4 __attribute__((ext_vector_type(4)));
typedef short short8 __attribute__((ext_vector_type(8)));
typedef unsigned int u32;

__device__ __forceinline__ unsigned short f2bf(float x) {
    unsigned u = __float_as_uint(x);
    u += 0x7FFFu + ((u >> 16) & 1u);
    return (unsigned short)(u >> 16);
}

// async 16B global -> LDS (DMA; LDS dest = wave-uniform base + lane*16)
__device__ __forceinline__ void gload16(const void* g, void* l) {
    __builtin_amdgcn_global_load_lds((const __attribute__((address_space(1))) u32*)g,
                                     (__attribute__((address_space(3))) u32*)l, 16, 0, 0);
}

// log-sum-exp merge of (m,s,t) stats; s==0 encodes "empty" (m == -inf)
__device__ __forceinline__ void merge3(float& m, float& s, float& t,
                                       float m2, float s2, float t2) {
    float mm = fmaxf(m, m2);
    float e1 = (s  > 0.f) ? __expf(m  - mm) : 0.f;
    float e2 = (s2 > 0.f) ? __expf(m2 - mm) : 0.f;
    s = s * e1 + s2 * e2;
    t = t * e1 + t2 * e2;
    m = mm;
}

// --- kernel 1: row squared-norms (fp32) + fp32 -> bf16 ----------------------
__global__ __launch_bounds__(256) void k_prep(const float* __restrict__ X,
                                              unsigned short* __restrict__ Xhi,
                                              float* __restrict__ sq) {
    const int row  = blockIdx.x * 4 + (threadIdx.x >> 6);
    const int lane = threadIdx.x & 63;
    const float4* xr = (const float4*)(X + (size_t)row * K);
    ushort4* hr = (ushort4*)(Xhi + (size_t)row * K);
    float s = 0.f;
#pragma unroll
    for (int i = 0; i < 8; ++i) {
        int idx = lane + i * 64;
        float4 v = xr[idx];
        ushort4 h;
        h.x = f2bf(v.x); h.y = f2bf(v.y); h.z = f2bf(v.z); h.w = f2bf(v.w);
        s += v.x * v.x + v.y * v.y + v.z * v.z + v.w * v.w;
        hr[idx] = h;
    }
#pragma unroll
    for (int off = 32; off > 0; off >>= 1) s += __shfl_xor(s, off);
    if (lane == 0) sq[row] = s;
}

// --- kernel 2: fused 128x128 bf16 Gram tile + partial softmax ---------------
__global__ __launch_bounds__(256, 4) void k_tile(const unsigned short* __restrict__ Xhi,
                                                 const int* __restrict__ tg,
                                                 const float* __restrict__ sq,
                                                 float* __restrict__ part) {
    __shared__ __align__(1024) char lds[32768]; // A (16KB) | B (16KB)
    const int tid = threadIdx.x;
    const int cb = blockIdx.x, rb = blockIdx.y;
    const int lane = tid & 63;
    const int wid = tid >> 6;
    const int wr = wid >> 1, wc = wid & 1;
    const int l15 = lane & 15, l4 = lane >> 4;

    // staging geometry: wave `wid` fills rows [wid*32, wid*32+32) of each
    // region in 4 instrs of 1024B (8 rows each). lane -> (row=lane>>3,
    // slot=lane&7); LDS is written LINEARLY, so the bank-conflict swizzle
    // (slot ^ (row&7)) is applied to the GLOBAL source column instead
    // (same involution applied on the read side).
    const int rsel = lane >> 3;          // row within 8-row group == row&7
    const int csel = (lane & 7) ^ rsel;  // pre-swizzled 16B column slot
    const char* gA = (const char*)(Xhi + (size_t)(rb * BM + wid * 32 + rsel) * K) + csel * 16;
    const char* gB = (const char*)(Xhi + (size_t)(cb * BN + wid * 32 + rsel) * K) + csel * 16;
    char* ldsA = lds + wid * 4096;
    char* ldsB = lds + 16384 + wid * 4096;

    f32x4 acc[4][4] = {};

    for (int kt = 0; kt < K / KT; ++kt) {
        __syncthreads(); // previous iter's ds_reads done before overwrite
        const size_t ko = (size_t)kt * (KT * 2);
#pragma unroll
        for (int j = 0; j < 4; ++j) {
            gload16(gA + ko + (size_t)j * (8 * K * 2), ldsA + j * 1024);
            gload16(gB + ko + (size_t)j * (8 * K * 2), ldsB + j * 1024);
        }
        __syncthreads(); // drains vmcnt -> tile resident
#pragma unroll
        for (int ks = 0; ks < 2; ++ks) {
            short8 ah[4], bh[4];
#pragma unroll
            for (int i = 0; i < 4; ++i) {
                int ar = wr * 64 + i * 16 + l15;
                int ao = ar * 128 + ((((ks << 2) | l4) ^ (ar & 7)) << 4);
                ah[i] = *(const short8*)(lds + ao);
                int br = wc * 64 + i * 16 + l15;
                int bo = br * 128 + ((((ks << 2) | l4) ^ (br & 7)) << 4);
                bh[i] = *(const short8*)(lds + 16384 + bo);
            }
#pragma unroll
            for (int mt = 0; mt < 4; ++mt)
#pragma unroll
                for (int nt = 0; nt < 4; ++nt)
                    acc[mt][nt] = __builtin_amdgcn_mfma_f32_16x16x32_bf16(ah[mt], bh[nt], acc[mt][nt], 0, 0, 0);
        }
    }

    // ---- epilogue: dist + per-row online-softmax partials over this col-block
    __syncthreads();
    float* sqA = (float*)lds;
    float* sqB = sqA + 128;
    int* tgA = (int*)(sqB + 128);
    int* tgB = tgA + 128;
    if (tid < 128) {
        sqA[tid] = sq[rb * BM + tid];
        sqB[tid] = sq[cb * BN + tid];
        tgA[tid] = tg[rb * BM + tid];
        tgB[tid] = tg[cb * BN + tid];
    }
    __syncthreads();
    float* stats = (float*)(lds + 8192); // [128 rows][2 wc][6] = 6KB

#pragma unroll
    for (int mt = 0; mt < 4; ++mt) {
#pragma unroll
        for (int rg = 0; rg < 4; ++rg) {
            int rl = wr * 64 + mt * 16 + l4 * 4 + rg;
            float sqi = sqA[rl];
            int ti = tgA[rl];
            float d[4]; bool ps[4];
            float mp = NEG_INF, mn = NEG_INF;
#pragma unroll
            for (int nt = 0; nt < 4; ++nt) {
                int cl = wc * 64 + nt * 16 + l15;
                float g = acc[mt][nt][rg];
                float dd = sqrtf(fmaxf(sqi + sqB[cl] - 2.0f * g, 1e-12f));
                d[nt] = dd;
                ps[nt] = (ti == tgB[cl]);
                if (ps[nt]) mp = fmaxf(mp, dd); else mn = fmaxf(mn, -dd);
            }
#pragma unroll
            for (int off = 1; off < 16; off <<= 1) {
                mp = fmaxf(mp, __shfl_xor(mp, off));
                mn = fmaxf(mn, __shfl_xor(mn, off));
            }
            float sp = 0.f, tp = 0.f, sn = 0.f, tn = 0.f;
#pragma unroll
            for (int nt = 0; nt < 4; ++nt) {
                float arg = ps[nt] ? (d[nt] - mp) : (-d[nt] - mn);
                float e = __expf(arg);
                if (ps[nt]) { sp += e; tp += e * d[nt]; }
                else        { sn += e; tn += e * d[nt]; }
            }
#pragma unroll
            for (int off = 1; off < 16; off <<= 1) {
                sp += __shfl_xor(sp, off);
                tp += __shfl_xor(tp, off);
                sn += __shfl_xor(sn, off);
                tn += __shfl_xor(tn, off);
            }
            if (l15 == 0) {
                float* p = stats + (rl * 2 + wc) * 6;
                p[0] = mp; p[1] = sp; p[2] = tp;
                p[3] = mn; p[4] = sn; p[5] = tn;
            }
        }
    }
    __syncthreads();
    if (tid < 128) {
        const float* a = stats + (tid * 2 + 0) * 6;
        const float* b = stats + (tid * 2 + 1) * 6;
        float mp = a[0], sp = a[1], tp = a[2];
        float mn = a[3], sn = a[4], tn = a[5];
        merge3(mp, sp, tp, b[0], b[1], b[2]);
        merge3(mn, sn, tn, b[3], b[4], b[5]);
        float* o = part + ((size_t)cb * N + rb * BM + tid) * 6;
        o[0] = mp; o[1] = sp; o[2] = tp;
        o[3] = mn; o[4] = sn; o[5] = tn;
    }
}

// --- kernel 3: merge col-block partials per row -> hinge ---------------------
__global__ __launch_bounds__(256) void k_rowmerge(const float* __restrict__ part,
                                                  float* __restrict__ hinge) {
    int r = blockIdx.x * 256 + threadIdx.x;
    float mp = NEG_INF, sp = 0.f, tp = 0.f;
    float mn = NEG_INF, sn = 0.f, tn = 0.f;
    for (int cb = 0; cb < NCB; ++cb) {
        const float* p = part + ((size_t)cb * N + r) * 6;
        merge3(mp, sp, tp, p[0], p[1], p[2]);
        merge3(mn, sn, tn, p[3], p[4], p[5]);
    }
    float dap = tp / sp;
    float dan = tn / sn;
    hinge[r] = fmaxf(dap - dan + 0.3f, 0.f);
}

// --- kernel 4: mean ----------------------------------------------------------
__global__ __launch_bounds__(256) void k_sum(const float* __restrict__ hinge,
                                             float* __restrict__ out) {
    float s = 0.f;
    for (int i = threadIdx.x; i < N; i += 256) s += hinge[i];
    __shared__ float red[256];
    red[threadIdx.x] = s;
    __syncthreads();
    for (int k = 128; k > 0; k >>= 1) {
        if (threadIdx.x < k) red[threadIdx.x] += red[threadIdx.x + k];
        __syncthreads();
    }
    if (threadIdx.x == 0) out[0] = red[0] * (1.0f / N);
}

extern "C" void kernel_launch(void* const* d_in, const int* in_sizes, int n_in,
                              void* d_out, int out_size, void* d_ws, size_t ws_size,
                              hipStream_t stream) {
    (void)in_sizes; (void)n_in; (void)out_size; (void)ws_size;
    const float* X  = (const float*)d_in[0];
    const int*   tg = (const int*)d_in[1];

    char* ws = (char*)d_ws;
    float* sq    = (float*)ws;                 // 16 KB
    float* hinge = (float*)(ws + 16384);       // 16 KB
    float* part  = (float*)(ws + 32768);       // 4096*32*6 floats = 3 MB
    unsigned short* Xhi = (unsigned short*)(ws + 3178496);   // 16 MB

    k_prep<<<N / 4, 256, 0, stream>>>(X, Xhi, sq);
    k_tile<<<dim3(NCB, NRB), 256, 0, stream>>>(Xhi, tg, sq, part);
    k_rowmerge<<<N / 256, 256, 0, stream>>>(part, hinge);
    k_sum<<<1, 256, 0, stream>>>(hinge, (float*)d_out);
}